// Round 6
// baseline (417.240 us; speedup 1.0000x reference)
//
#include <hip/hip_runtime.h>
#include <hip/hip_bf16.h>

typedef __bf16 bf16x8 __attribute__((ext_vector_type(8)));
typedef float f32x4 __attribute__((ext_vector_type(4)));

#define MFMA16(a,b,c) __builtin_amdgcn_mfma_f32_16x16x32_bf16(a,b,c,0,0,0)
#define GLL16(src, dst) __builtin_amdgcn_global_load_lds( \
    (const __attribute__((address_space(1))) unsigned int*)(src), \
    (__attribute__((address_space(3))) unsigned int*)(dst), 16, 0, 0)

__device__ inline unsigned int pack_bf16(float a, float b) {
    unsigned short ua = __builtin_bit_cast(unsigned short, (__bf16)a);
    unsigned short ub = __builtin_bit_cast(unsigned short, (__bf16)b);
    return ((unsigned int)ub << 16) | ua;
}
__device__ inline short bf_s(float v) {
    __bf16 b = (__bf16)v;
    return __builtin_bit_cast(short, b);
}

// ---------------------------------------------------------------------------
// fp32 -> bf16 (once per element)
// ---------------------------------------------------------------------------
__global__ void cvt_f32_bf16(const float* __restrict__ in,
                             __hip_bfloat16* __restrict__ out, int n) {
    int i = (blockIdx.x * blockDim.x + threadIdx.x) * 8;
    if (i >= n) return;
    float4 a = *(const float4*)(in + i);
    float4 b = *(const float4*)(in + i + 4);
    bf16x8 r;
    r[0] = (__bf16)a.x; r[1] = (__bf16)a.y; r[2] = (__bf16)a.z; r[3] = (__bf16)a.w;
    r[4] = (__bf16)b.x; r[5] = (__bf16)b.y; r[6] = (__bf16)b.z; r[7] = (__bf16)b.w;
    *(bf16x8*)((__bf16*)out + i) = r;
}

// ---------------------------------------------------------------------------
// 128xBN GEMM, C = scale * A·B^T, 1-barrier double-buffered pipeline:
//   stage(0); loop { barrier; stage(it+1)->buf^1; compute(it)->buf }
// The barrier's vmcnt(0) drain waits on loads issued one full compute earlier.
// Frag-order LDS (lane-linear ds_read_b128, conflict-free by construction).
// VT: cols >= split are the V projection, written TRANSPOSED to C1[b][d][tok].
// ---------------------------------------------------------------------------
template <int BN, bool VT>
__global__ __launch_bounds__(256) void gemm_tile(const __bf16* __restrict__ A,
                                                 const __bf16* __restrict__ B,
                                                 __bf16* __restrict__ C0,
                                                 __bf16* __restrict__ C1,
                                                 int K, int tilesN, int split, int ldc,
                                                 float scale) {
    constexpr int BBLK = BN / 16;
    constexpr int JT = BN / 32;
    constexpr int AH = 8 * 512;
    constexpr int BH = BBLK * 512;
    __shared__ __bf16 As[2 * AH];
    __shared__ __bf16 Bs[2 * BH];

    int tid = threadIdx.x;
    int wave = tid >> 6, lane = tid & 63;
    int quad = lane >> 4, l16 = lane & 15;

    int tm = blockIdx.x / tilesN, tn = blockIdx.x % tilesN;

    const __bf16* Abase = A + (size_t)tm * 128 * K + (size_t)l16 * K + quad * 8;
    const __bf16* Bbase = B + (size_t)tn * BN * K + (size_t)l16 * K + quad * 8;

    f32x4 acc[4][JT] = {};

    auto stage = [&](int kt, int buf) {
#pragma unroll
        for (int rr = 0; rr < 2; ++rr) {
            int fb = rr * 4 + wave;
            GLL16(Abase + (size_t)fb * 16 * K + kt, As + buf * AH + fb * 512 + lane * 8);
        }
#pragma unroll
        for (int rr = 0; rr < BBLK / 4; ++rr) {
            int fb = rr * 4 + wave;
            GLL16(Bbase + (size_t)fb * 16 * K + kt, Bs + buf * BH + fb * 512 + lane * 8);
        }
    };

    int nk = K >> 5;
    stage(0, 0);
    for (int it = 0; it < nk; ++it) {
        __syncthreads();
        if (it + 1 < nk) stage((it + 1) << 5, (it + 1) & 1);
        const __bf16* Ab = As + (it & 1) * AH;
        const __bf16* Bb = Bs + (it & 1) * BH;
        bf16x8 af[4], bfr[JT];
#pragma unroll
        for (int i = 0; i < 4; ++i)
            af[i] = *(const bf16x8*)(Ab + ((wave >> 1) * 4 + i) * 512 + lane * 8);
#pragma unroll
        for (int j = 0; j < JT; ++j)
            bfr[j] = *(const bf16x8*)(Bb + ((wave & 1) * (BBLK / 2) + j) * 512 + lane * 8);
#pragma unroll
        for (int i = 0; i < 4; ++i)
#pragma unroll
            for (int j = 0; j < JT; ++j)
                acc[i][j] = MFMA16(af[i], bfr[j], acc[i][j]);
    }

    int colbase = tn * BN + (wave & 1) * (BN / 2);
#pragma unroll
    for (int i = 0; i < 4; ++i) {
        int row = tm * 128 + (wave >> 1) * 64 + i * 16 + quad * 4;
#pragma unroll
        for (int j = 0; j < JT; ++j) {
            int col = colbase + j * 16 + l16;
            if (!VT || col < split) {
#pragma unroll
                for (int r = 0; r < 4; ++r)
                    C0[(size_t)(row + r) * ldc + col] = (__bf16)(acc[i][j][r] * scale);
            } else {
                // V^T[b][d][tok]: rows r = 4 consecutive tokens -> one short4
                int d = col - split;
                int bb = row >> 11, tok = row & 2047;
                short4 pk;
                pk.x = bf_s(acc[i][j][0] * scale);
                pk.y = bf_s(acc[i][j][1] * scale);
                pk.z = bf_s(acc[i][j][2] * scale);
                pk.w = bf_s(acc[i][j][3] * scale);
                *(short4*)(C1 + (size_t)bb * 1048576 + (size_t)d * 2048 + tok) = pk;
            }
        }
    }
}

// ---------------------------------------------------------------------------
// Flash attention, no K/V LDS, no barriers. Block = (b,g,head-pair,64-q);
// 2 waves, each one head. K-frags and V^T-frags are read DIRECTLY from global
// (L2-resident per (b,g), bg = bid&7 aligns with XCD). P goes through a small
// frag-order LDS (wave-private, lane-linear reads).
// qb pairing: blocks bid and bid+256 share a CU; qb sums constant -> balanced.
// ---------------------------------------------------------------------------
__global__ __launch_bounds__(128) void attn_mfma(const __bf16* __restrict__ Q,
                                                 const __bf16* __restrict__ Kb,
                                                 const __bf16* __restrict__ Vtg,
                                                 float* __restrict__ O) {
    const int T = 2048, DKV = 512, HD = 128, CM = 2048;
    __shared__ __bf16 Pl[2 * 4096];   // 16 KB

    int tid = threadIdx.x;
    int wave = tid >> 6, lane = tid & 63;
    int quad = lane >> 4, l16 = lane & 15;

    int bg = blockIdx.x & 7;
    int hp = (blockIdx.x >> 3) & 1;
    int slot = blockIdx.x >> 4;                      // 0..31
    int qb = (slot < 16) ? (31 - slot) : (slot - 16);
    int b = bg >> 2, g = bg & 3;
    int h = g * 4 + hp * 2 + wave;
    int q0 = qb * 64;

    // Q fragments (b-operand): lane holds Q[q0+nt*16+l16][dt*32+quad*8 ..+8]
    bf16x8 qf[4][4];
    const __bf16* qbase = Q + (size_t)b * T * CM + (size_t)h * HD;
#pragma unroll
    for (int nt = 0; nt < 4; ++nt)
#pragma unroll
        for (int dt = 0; dt < 4; ++dt)
            qf[nt][dt] = *(const bf16x8*)(qbase + (size_t)(q0 + nt * 16 + l16) * CM
                                          + dt * 32 + quad * 8);

    const __bf16* kgb = Kb + (size_t)b * T * DKV + g * HD;            // K[tok][512]
    const __bf16* vgb = Vtg + (size_t)b * DKV * T + (size_t)g * HD * T; // V^T[128][2048]

    float m_r[4], l_r[4];
    f32x4 o_acc[4][8] = {};
#pragma unroll
    for (int i = 0; i < 4; ++i) { m_r[i] = -1e30f; l_r[i] = 0.f; }

    __bf16* Pw = Pl + wave * 4096;

    int nch = qb + 1;
    for (int ch = 0; ch < nch; ++ch) {
        int j0 = ch * 64;
        bool diag = (ch == nch - 1);

        // ---- S^T = K·Q^T, K a-frags straight from global (L2) ----
        f32x4 st[4][4];
#pragma unroll
        for (int nt = 0; nt < 4; ++nt)
#pragma unroll
            for (int t = 0; t < 4; ++t) st[nt][t] = f32x4{0.f, 0.f, 0.f, 0.f};
#pragma unroll
        for (int t = 0; t < 4; ++t)
#pragma unroll
            for (int dt = 0; dt < 4; ++dt) {
                bf16x8 kf = *(const bf16x8*)(kgb + (size_t)(j0 + t * 16 + l16) * DKV
                                             + dt * 32 + quad * 8);
#pragma unroll
                for (int nt = 0; nt < 4; ++nt)
                    st[nt][t] = MFMA16(kf, qf[nt][dt], st[nt][t]);
            }

        // ---- prefetch V^T frags (global, consumed after softmax) ----
        bf16x8 vt[16];
#pragma unroll
        for (int f = 0; f < 16; ++f) {
            int nto = f >> 1, kk = f & 1;
            vt[f] = *(const bf16x8*)(vgb + (size_t)(nto * 16 + l16) * T
                                     + j0 + kk * 32 + quad * 8);
        }

        // ---- mask (diag only) + online softmax; P -> frag-order LDS ----
        float alpha[4];
#pragma unroll
        for (int nt = 0; nt < 4; ++nt) {
            if (diag) {
                int qg = nt * 16 + l16;
#pragma unroll
                for (int t = 0; t < 4; ++t)
#pragma unroll
                    for (int r = 0; r < 4; ++r)
                        if (t * 16 + quad * 4 + r > qg) st[nt][t][r] = -1e30f;
            }
            float cmax = -1e30f;
#pragma unroll
            for (int t = 0; t < 4; ++t)
                cmax = fmaxf(cmax, fmaxf(fmaxf(st[nt][t][0], st[nt][t][1]),
                                         fmaxf(st[nt][t][2], st[nt][t][3])));
            cmax = fmaxf(cmax, __shfl_xor(cmax, 16));
            cmax = fmaxf(cmax, __shfl_xor(cmax, 32));
            float mnew = fmaxf(m_r[nt], cmax);
            alpha[nt] = __expf(m_r[nt] - mnew);
            m_r[nt] = mnew;
            float ps = 0.f;
#pragma unroll
            for (int t = 0; t < 4; ++t) {
                float p0 = __expf(st[nt][t][0] - mnew);
                float p1 = __expf(st[nt][t][1] - mnew);
                float p2 = __expf(st[nt][t][2] - mnew);
                float p3 = __expf(st[nt][t][3] - mnew);
                ps += (p0 + p1) + (p2 + p3);
                // frag-order: block (nt*2 + (t>>1)), elem ((t&1)*2+(quad>>1))*128
                //             + l16*8 + (quad&1)*4  (+r), 4 elems = one b64
                int off = (nt * 2 + (t >> 1)) * 512 + ((t & 1) * 2 + (quad >> 1)) * 128
                          + l16 * 8 + (quad & 1) * 4;
                unsigned long long pk =
                    (unsigned long long)pack_bf16(p0, p1) |
                    ((unsigned long long)pack_bf16(p2, p3) << 32);
                *(unsigned long long*)(Pw + off) = pk;
            }
            ps += __shfl_xor(ps, 16);
            ps += __shfl_xor(ps, 32);
            l_r[nt] = l_r[nt] * alpha[nt] + ps;
        }

        // ---- rescale O by alpha (q redistributed l16 -> quad*4+r) ----
#pragma unroll
        for (int mt = 0; mt < 4; ++mt)
#pragma unroll
            for (int r = 0; r < 4; ++r) {
                float alr = __shfl(alpha[mt], quad * 4 + r);
#pragma unroll
                for (int nto = 0; nto < 8; ++nto)
                    o_acc[mt][nto][r] *= alr;
            }

        // ---- O += P·V, P a-frags lane-linear from LDS, V^T b-frags in regs ----
#pragma unroll
        for (int mt = 0; mt < 4; ++mt)
#pragma unroll
            for (int kk = 0; kk < 2; ++kk) {
                bf16x8 pf = *(const bf16x8*)(Pw + (mt * 2 + kk) * 512 + lane * 8);
#pragma unroll
                for (int nto = 0; nto < 8; ++nto)
                    o_acc[mt][nto] = MFMA16(pf, vt[(nto << 1) | kk], o_acc[mt][nto]);
            }
    }

    // ---- epilogue ----
    float* obase = O + (size_t)b * T * CM + (size_t)h * HD;
#pragma unroll
    for (int mt = 0; mt < 4; ++mt) {
        float invl = 1.f / l_r[mt];
#pragma unroll
        for (int r = 0; r < 4; ++r) {
            float ir = __shfl(invl, quad * 4 + r);
            float* orow = obase + (size_t)(q0 + 16 * mt + quad * 4 + r) * CM;
#pragma unroll
            for (int nto = 0; nto < 8; ++nto)
                orow[nto * 16 + l16] = o_acc[mt][nto][r] * ir;
        }
    }
}

extern "C" void kernel_launch(void* const* d_in, const int* in_sizes, int n_in,
                              void* d_out, int out_size, void* d_ws, size_t ws_size,
                              hipStream_t stream) {
    const float* x  = (const float*)d_in[0];   // [2,2048,2048]
    const float* Wq = (const float*)d_in[1];   // [2048,2048]
    const float* Wk = (const float*)d_in[2];   // [512,2048]
    const float* Wv = (const float*)d_in[3];   // [512,2048]
    float* out = (float*)d_out;

    const float qscale = 0.08838834764831845f; // 128^-0.5 folded into Q proj

    __hip_bfloat16* xb  = (__hip_bfloat16*)d_ws;         // 8M elem
    __hip_bfloat16* Wqb = xb + 8388608;                  // 4M
    __hip_bfloat16* Wkb = Wqb + 4194304;                 // 1M (Wkb+Wvb contiguous)
    __hip_bfloat16* Wvb = Wkb + 1048576;                 // 1M
    __hip_bfloat16* Qb  = Wvb + 1048576;                 // 8M
    __hip_bfloat16* Kbf = Qb + 8388608;                  // 2M
    __hip_bfloat16* Vtg = Kbf + 2097152;                 // 2M  V^T [b][512][2048]

    cvt_f32_bf16<<<4096, 256, 0, stream>>>(x,  xb,  8388608);
    cvt_f32_bf16<<<2048, 256, 0, stream>>>(Wq, Wqb, 4194304);
    cvt_f32_bf16<<< 512, 256, 0, stream>>>(Wk, Wkb, 1048576);
    cvt_f32_bf16<<< 512, 256, 0, stream>>>(Wv, Wvb, 1048576);

    gemm_tile<128, false><<<512, 256, 0, stream>>>(
        (const __bf16*)xb, (const __bf16*)Wqb, (__bf16*)Qb, nullptr,
        2048, 16, 1 << 30, 2048, qscale);
    gemm_tile<64, true><<<512, 256, 0, stream>>>(
        (const __bf16*)xb, (const __bf16*)Wkb, (__bf16*)Kbf, (__bf16*)Vtg,
        2048, 16, 512, 512, 1.f);

    attn_mfma<<<512, 128, 0, stream>>>((const __bf16*)Qb, (const __bf16*)Kbf,
                                       (const __bf16*)Vtg, out);
}

// Round 7
// 278.420 us; speedup vs baseline: 1.4986x; 1.4986x over previous
//
#include <hip/hip_runtime.h>
#include <hip/hip_bf16.h>

typedef __bf16 bf16x8 __attribute__((ext_vector_type(8)));
typedef float f32x4 __attribute__((ext_vector_type(4)));

#define MFMA16(a,b,c) __builtin_amdgcn_mfma_f32_16x16x32_bf16(a,b,c,0,0,0)
#define GLL16(src, dst) __builtin_amdgcn_global_load_lds( \
    (const __attribute__((address_space(1))) unsigned int*)(src), \
    (__attribute__((address_space(3))) unsigned int*)(dst), 16, 0, 0)

__device__ inline unsigned int pack_bf16(float a, float b) {
    unsigned short ua = __builtin_bit_cast(unsigned short, (__bf16)a);
    unsigned short ub = __builtin_bit_cast(unsigned short, (__bf16)b);
    return ((unsigned int)ub << 16) | ua;
}
__device__ inline short bf_s(float v) {
    __bf16 b = (__bf16)v;
    return __builtin_bit_cast(short, b);
}

// ---------------------------------------------------------------------------
// Fused fp32->bf16: x -> xb, Wq/Wk/Wv -> Wb rows [0,2048)/[2048,2560)/[2560,3072)
// ---------------------------------------------------------------------------
__global__ void cvt_all(const float* __restrict__ x,  const float* __restrict__ wq,
                        const float* __restrict__ wk, const float* __restrict__ wv,
                        __bf16* __restrict__ xb, __bf16* __restrict__ wb) {
    long i = (long)(blockIdx.x * blockDim.x + threadIdx.x) * 8;
    const float* src; __bf16* dst;
    if (i < 8388608)       { src = x  + i;              dst = xb + i; }
    else if (i < 12582912) { src = wq + (i - 8388608);  dst = wb + (i - 8388608); }
    else if (i < 13631488) { src = wk + (i - 12582912); dst = wb + (i - 12582912 + 4194304); }
    else                   { src = wv + (i - 13631488); dst = wb + (i - 13631488 + 5242880); }
    float4 a = *(const float4*)src;
    float4 b = *(const float4*)(src + 4);
    bf16x8 r;
    r[0] = (__bf16)a.x; r[1] = (__bf16)a.y; r[2] = (__bf16)a.z; r[3] = (__bf16)a.w;
    r[4] = (__bf16)b.x; r[5] = (__bf16)b.y; r[6] = (__bf16)b.z; r[7] = (__bf16)b.w;
    *(bf16x8*)dst = r;
}

// ---------------------------------------------------------------------------
// Fused QKV GEMM: C = A·B^T, A=[4096][2048], B=[3072][2048] (Wq|Wk|Wv rows).
// 128x128 tiles, 1-barrier double-buffered global_load_lds(16B) pipeline,
// frag-order LDS (lane-linear, conflict-free). Epilogue routes by tn:
//   tn<16:  Q row-major (scaled by 128^-0.5)
//   16..19: K -> Kf frag-order  [b][g][tb=tok/16][dt=k/32][512]
//   20..23: V -> Vf frag-order  [b][g][ch=tok/64][fb=(d/16)*2+(tok/32)%2][512]
// so attention can stage K/V chunks as contiguous 1KB global_load_lds blocks.
// ---------------------------------------------------------------------------
__global__ __launch_bounds__(256) void gemm_qkv(const __bf16* __restrict__ A,
                                                const __bf16* __restrict__ B,
                                                __bf16* __restrict__ Qb,
                                                __bf16* __restrict__ Kf,
                                                __bf16* __restrict__ Vf,
                                                float qscale) {
    const int K = 2048;
    __shared__ __bf16 As[2 * 4096];
    __shared__ __bf16 Bs[2 * 4096];

    int tid = threadIdx.x;
    int wave = tid >> 6, lane = tid & 63;
    int quad = lane >> 4, l16 = lane & 15;

    int tm = blockIdx.x & 31, tn = blockIdx.x >> 5;

    const __bf16* Abase = A + (size_t)tm * 128 * K + (size_t)l16 * K + quad * 8;
    const __bf16* Bbase = B + (size_t)tn * 128 * K + (size_t)l16 * K + quad * 8;

    f32x4 acc[4][4] = {};

    auto stage = [&](int kt, int buf) {
#pragma unroll
        for (int rr = 0; rr < 2; ++rr) {
            int fb = rr * 4 + wave;
            GLL16(Abase + (size_t)fb * 16 * K + kt, As + buf * 4096 + fb * 512 + lane * 8);
            GLL16(Bbase + (size_t)fb * 16 * K + kt, Bs + buf * 4096 + fb * 512 + lane * 8);
        }
    };

    const int nk = K >> 5;
    stage(0, 0);
    for (int it = 0; it < nk; ++it) {
        __syncthreads();
        if (it + 1 < nk) stage((it + 1) << 5, (it + 1) & 1);
        const __bf16* Ab = As + (it & 1) * 4096;
        const __bf16* Bb = Bs + (it & 1) * 4096;
        bf16x8 af[4], bfr[4];
#pragma unroll
        for (int i = 0; i < 4; ++i)
            af[i] = *(const bf16x8*)(Ab + ((wave >> 1) * 4 + i) * 512 + lane * 8);
#pragma unroll
        for (int j = 0; j < 4; ++j)
            bfr[j] = *(const bf16x8*)(Bb + ((wave & 1) * 4 + j) * 512 + lane * 8);
#pragma unroll
        for (int i = 0; i < 4; ++i)
#pragma unroll
            for (int j = 0; j < 4; ++j)
                acc[i][j] = MFMA16(af[i], bfr[j], acc[i][j]);
    }

    int colbase = tn * 128 + (wave & 1) * 64;
#pragma unroll
    for (int i = 0; i < 4; ++i) {
        int row0 = tm * 128 + (wave >> 1) * 64 + i * 16 + quad * 4;
        int b = row0 >> 11, tok0 = row0 & 2047;
#pragma unroll
        for (int j = 0; j < 4; ++j) {
            int col = colbase + j * 16 + l16;
            if (tn < 16) {                       // ---- Q, row-major ----
#pragma unroll
                for (int r = 0; r < 4; ++r)
                    Qb[(size_t)(row0 + r) * 2048 + col] = (__bf16)(acc[i][j][r] * qscale);
            } else if (tn < 20) {                // ---- K frag-order ----
                int d_all = col - 2048;
                int g = d_all >> 7, dd = d_all & 127;
                int dt = dd >> 5, q4 = (dd >> 3) & 3, jj = dd & 7;
                int tb = tok0 >> 4, tl0 = tok0 & 15;
                __bf16* base = Kf + ((((size_t)(b * 4 + g) * 128 + tb) * 4 + dt) * 512)
                               + (q4 * 16 + tl0) * 8 + jj;
#pragma unroll
                for (int r = 0; r < 4; ++r)
                    base[r * 8] = (__bf16)acc[i][j][r];
            } else {                             // ---- V frag-order ----
                int d_all = col - 2560;
                int g = d_all >> 7, dd = d_all & 127;
                int nto = dd >> 4, dl = dd & 15;
                int ch = tok0 >> 6, kk = (tok0 >> 5) & 1;
                int q4v = (tok0 >> 3) & 3, jv0 = tok0 & 7;
                size_t off = ((((size_t)(b * 4 + g) * 32 + ch) * 16) + nto * 2 + kk) * 512
                             + (q4v * 16 + dl) * 8 + jv0;
                short4 pk;
                pk.x = bf_s(acc[i][j][0]); pk.y = bf_s(acc[i][j][1]);
                pk.z = bf_s(acc[i][j][2]); pk.w = bf_s(acc[i][j][3]);
                *(short4*)(Vf + off) = pk;
            }
        }
    }
}

// ---------------------------------------------------------------------------
// Flash attention. Block = (b,g,qb); 4 waves = 4 heads share K/V LDS chunks
// staged via global_load_lds from frag-order Kf/Vf (coalesced 1KB per instr,
// lane-linear ds_read_b128 = conflict-free). P: wave-private frag-order LDS
// round-trip (no barrier). 2 barriers/chunk, 48KB LDS -> 2+ blocks/CU.
// qb pairing: slots (63-s, s-32) make per-CU work ~constant.
// ---------------------------------------------------------------------------
__global__ __launch_bounds__(256) void attn_mfma(const __bf16* __restrict__ Q,
                                                 const __bf16* __restrict__ Kf,
                                                 const __bf16* __restrict__ Vf,
                                                 float* __restrict__ O) {
    const int T = 2048, CM = 2048, HD = 128;
    __shared__ __bf16 Ks[8192];   // 16 KB: fb = t*4+dt
    __shared__ __bf16 Vs[8192];   // 16 KB: fb = nto*2+kk
    __shared__ __bf16 Pl[8192];   // 4 KB/wave: fb = mt*2+kk

    int tid = threadIdx.x;
    int wave = tid >> 6, lane = tid & 63;
    int quad = lane >> 4, l16 = lane & 15;

    int bg = blockIdx.x & 7;
    int slot = blockIdx.x >> 3;
    int qb = (slot < 32) ? (63 - slot) : (slot - 32);
    int b = bg >> 2, g = bg & 3;
    int h = g * 4 + wave;
    int q0 = qb * 32;

    bf16x8 qf[2][4];
    const __bf16* qbase = Q + (size_t)b * T * CM + (size_t)h * HD;
#pragma unroll
    for (int nt = 0; nt < 2; ++nt)
#pragma unroll
        for (int dt = 0; dt < 4; ++dt)
            qf[nt][dt] = *(const bf16x8*)(qbase + (size_t)(q0 + nt * 16 + l16) * CM
                                          + dt * 32 + quad * 8);

    const __bf16* kcb = Kf + (size_t)(b * 4 + g) * 262144;
    const __bf16* vcb = Vf + (size_t)(b * 4 + g) * 262144;

    float m_r[2] = {-1e30f, -1e30f}, l_r[2] = {0.f, 0.f};
    f32x4 o_acc[2][8] = {};
    __bf16* Pw = Pl + wave * 2048;

    int nch = (qb >> 1) + 1;
    for (int ch = 0; ch < nch; ++ch) {
        __syncthreads();   // previous compute done -> safe to overwrite K/V LDS
        {
            const __bf16* kg = kcb + ch * 8192 + wave * 2048 + lane * 8;
            const __bf16* vg = vcb + ch * 8192 + wave * 2048 + lane * 8;
            __bf16* kl = Ks + wave * 2048 + lane * 8;
            __bf16* vl = Vs + wave * 2048 + lane * 8;
#pragma unroll
            for (int i = 0; i < 4; ++i) GLL16(kg + i * 512, kl + i * 512);
#pragma unroll
            for (int i = 0; i < 4; ++i) GLL16(vg + i * 512, vl + i * 512);
        }
        __syncthreads();   // drain staging

        // ---- S^T = K·Q^T ----
        f32x4 st[2][4] = {};
#pragma unroll
        for (int t = 0; t < 4; ++t)
#pragma unroll
            for (int dt = 0; dt < 4; ++dt) {
                bf16x8 kfv = *(const bf16x8*)(Ks + (t * 4 + dt) * 512 + lane * 8);
                st[0][t] = MFMA16(kfv, qf[0][dt], st[0][t]);
                st[1][t] = MFMA16(kfv, qf[1][dt], st[1][t]);
            }

        bool diag = (ch == nch - 1);
        float alpha[2];
#pragma unroll
        for (int nt = 0; nt < 2; ++nt) {
            if (diag) {
                int qg = q0 + nt * 16 + l16;
#pragma unroll
                for (int t = 0; t < 4; ++t)
#pragma unroll
                    for (int r = 0; r < 4; ++r)
                        if (ch * 64 + t * 16 + quad * 4 + r > qg) st[nt][t][r] = -1e30f;
            }
            float cmax = -1e30f;
#pragma unroll
            for (int t = 0; t < 4; ++t)
                cmax = fmaxf(cmax, fmaxf(fmaxf(st[nt][t][0], st[nt][t][1]),
                                         fmaxf(st[nt][t][2], st[nt][t][3])));
            cmax = fmaxf(cmax, __shfl_xor(cmax, 16));
            cmax = fmaxf(cmax, __shfl_xor(cmax, 32));
            float mnew = fmaxf(m_r[nt], cmax);
            alpha[nt] = __expf(m_r[nt] - mnew);
            m_r[nt] = mnew;
            float ps = 0.f;
#pragma unroll
            for (int t = 0; t < 4; ++t) {
                float p0 = __expf(st[nt][t][0] - mnew);
                float p1 = __expf(st[nt][t][1] - mnew);
                float p2 = __expf(st[nt][t][2] - mnew);
                float p3 = __expf(st[nt][t][3] - mnew);
                ps += (p0 + p1) + (p2 + p3);
                int off = (nt * 2 + (t >> 1)) * 512 + ((t & 1) * 2 + (quad >> 1)) * 128
                          + l16 * 8 + (quad & 1) * 4;
                unsigned long long pk =
                    (unsigned long long)pack_bf16(p0, p1) |
                    ((unsigned long long)pack_bf16(p2, p3) << 32);
                *(unsigned long long*)(Pw + off) = pk;
            }
            ps += __shfl_xor(ps, 16);
            ps += __shfl_xor(ps, 32);
            l_r[nt] = l_r[nt] * alpha[nt] + ps;
        }

        // ---- rescale O ----
#pragma unroll
        for (int mt = 0; mt < 2; ++mt)
#pragma unroll
            for (int r = 0; r < 4; ++r) {
                float alr = __shfl(alpha[mt], quad * 4 + r);
#pragma unroll
                for (int nto = 0; nto < 8; ++nto)
                    o_acc[mt][nto][r] *= alr;
            }

        // ---- O += P·V (P wave-private: no barrier; lgkmcnt orders WAR/RAW) ----
#pragma unroll
        for (int mt = 0; mt < 2; ++mt)
#pragma unroll
            for (int kk = 0; kk < 2; ++kk) {
                bf16x8 pf = *(const bf16x8*)(Pw + (mt * 2 + kk) * 512 + lane * 8);
#pragma unroll
                for (int nto = 0; nto < 8; ++nto) {
                    bf16x8 vf = *(const bf16x8*)(Vs + (nto * 2 + kk) * 512 + lane * 8);
                    o_acc[mt][nto] = MFMA16(pf, vf, o_acc[mt][nto]);
                }
            }
    }

    float* obase = O + (size_t)b * T * CM + (size_t)h * HD;
#pragma unroll
    for (int mt = 0; mt < 2; ++mt) {
        float invl = 1.f / l_r[mt];
#pragma unroll
        for (int r = 0; r < 4; ++r) {
            float ir = __shfl(invl, quad * 4 + r);
            float* orow = obase + (size_t)(q0 + 16 * mt + quad * 4 + r) * CM;
#pragma unroll
            for (int nto = 0; nto < 8; ++nto)
                orow[nto * 16 + l16] = o_acc[mt][nto][r] * ir;
        }
    }
}

extern "C" void kernel_launch(void* const* d_in, const int* in_sizes, int n_in,
                              void* d_out, int out_size, void* d_ws, size_t ws_size,
                              hipStream_t stream) {
    const float* x  = (const float*)d_in[0];
    const float* Wq = (const float*)d_in[1];
    const float* Wk = (const float*)d_in[2];
    const float* Wv = (const float*)d_in[3];
    float* out = (float*)d_out;

    const float qscale = 0.08838834764831845f;  // 128^-0.5

    __bf16* xb = (__bf16*)d_ws;              // 8M elems
    __bf16* Wb = xb + 8388608;               // 6M  [3072][2048] = Wq|Wk|Wv
    __bf16* Qb = Wb + 6291456;               // 8M  [4096][2048]
    __bf16* Kfr = Qb + 8388608;              // 2M  frag-order K
    __bf16* Vfr = Kfr + 2097152;             // 2M  frag-order V

    cvt_all<<<7168, 256, 0, stream>>>(x, Wq, Wk, Wv, xb, Wb);
    gemm_qkv<<<768, 256, 0, stream>>>(xb, Wb, Qb, Kfr, Vfr, qscale);
    attn_mfma<<<512, 256, 0, stream>>>(Qb, Kfr, Vfr, out);
}